// Round 1
// baseline (5468.002 us; speedup 1.0000x reference)
//
#include <hip/hip_runtime.h>
#include <cmath>

#define NB 4
#define TT 2048
#define DD 256
#define NH 4
#define HDIM 64
#define BT (NB*TT)   // 8192 rows

static constexpr float DT_ = 0.25f;

// ---------------- row-wise l2 norm over D=256 (one wave per row) ----------------
__global__ __launch_bounds__(256)
void l2norm_rows(const float* __restrict__ src, float* __restrict__ dst) {
    const int wave = threadIdx.x >> 6;
    const int lane = threadIdx.x & 63;
    const size_t row = (size_t)blockIdx.x * 4 + wave;
    float4 v = ((const float4*)(src + row * DD))[lane];
    float ss = v.x*v.x + v.y*v.y + v.z*v.z + v.w*v.w;
    #pragma unroll
    for (int off = 32; off; off >>= 1) ss += __shfl_xor(ss, off, 64);
    const float inv = 1.0f / fmaxf(sqrtf(ss), 1e-12f);
    v.x *= inv; v.y *= inv; v.z *= inv; v.w *= inv;
    ((float4*)(dst + row * DD))[lane] = v;
}

// ---------------- per-head l2 norm of q and k (qk layout [BT, 512]) ----------------
// wave w of the block handles head w: q cols w*64.., k cols 256+w*64..
__global__ __launch_bounds__(256)
void qk_headnorm(float* __restrict__ qk) {
    const int wave = threadIdx.x >> 6;
    const int lane = threadIdx.x & 63;
    float* row = qk + (size_t)blockIdx.x * 512;
    const int qo = wave * 64 + lane;
    const int ko = 256 + wave * 64 + lane;
    float qv = row[qo];
    float kv = row[ko];
    float qs = qv * qv, ks = kv * kv;
    #pragma unroll
    for (int off = 32; off; off >>= 1) {
        qs += __shfl_xor(qs, off, 64);
        ks += __shfl_xor(ks, off, 64);
    }
    row[qo] = qv / fmaxf(sqrtf(qs), 1e-12f);
    row[ko] = kv / fmaxf(sqrtf(ks), 1e-12f);
}

// ---------------- C = A[M,256] * W[N,256]^T, 64x64 tile, 4x4 per thread ----------------
// stage < 0 : plain store to C (N = 512, the qk GEMM)
// stage 0..3: N = 256; f = acc + omega + bout; RK4 epilogue:
//   s=0: kacc = f;        xs = x + dt/2 * f
//   s=1: kacc += 2f;      xs = x + dt/2 * f
//   s=2: kacc += 2f;      xs = x + dt   * f
//   s=3: xout = x + dt/6 * (kacc + f)
__global__ __launch_bounds__(256)
void gemm_nt_fused(const float* __restrict__ A, const float* __restrict__ W,
                   float* __restrict__ C, int N,
                   const float* __restrict__ omega, const float* __restrict__ bout,
                   const float* __restrict__ xin, float* __restrict__ kacc,
                   float* __restrict__ xstage, float* __restrict__ xout, int stage)
{
    __shared__ float At[64][68];
    __shared__ float Wt[64][68];
    const int m0 = blockIdx.x * 64, n0 = blockIdx.y * 64;
    const int t  = threadIdx.x;
    const int lr = t >> 4;
    const int lc = (t & 15) << 2;
    const int ty4 = (t >> 4) << 2;   // row offset of 4x4 tile
    const int tx4 = (t & 15) << 2;   // col offset of 4x4 tile
    float acc[4][4] = {};
    for (int k0 = 0; k0 < 256; k0 += 64) {
        __syncthreads();
        #pragma unroll
        for (int rr = 0; rr < 4; ++rr) {
            const int r = lr + rr * 16;
            float4 av = *(const float4*)(A + (size_t)(m0 + r) * 256 + k0 + lc);
            At[lc+0][r] = av.x; At[lc+1][r] = av.y; At[lc+2][r] = av.z; At[lc+3][r] = av.w;
            float4 wv = *(const float4*)(W + (size_t)(n0 + r) * 256 + k0 + lc);
            Wt[lc+0][r] = wv.x; Wt[lc+1][r] = wv.y; Wt[lc+2][r] = wv.z; Wt[lc+3][r] = wv.w;
        }
        __syncthreads();
        #pragma unroll 8
        for (int k = 0; k < 64; ++k) {
            float4 av = *(const float4*)&At[k][ty4];
            float4 wv = *(const float4*)&Wt[k][tx4];
            const float a[4] = {av.x, av.y, av.z, av.w};
            const float w[4] = {wv.x, wv.y, wv.z, wv.w};
            #pragma unroll
            for (int i = 0; i < 4; ++i)
                #pragma unroll
                for (int j = 0; j < 4; ++j)
                    acc[i][j] = fmaf(a[i], w[j], acc[i][j]);
        }
    }
    const int cn = n0 + tx4;
    if (stage < 0) {
        #pragma unroll
        for (int i = 0; i < 4; ++i) {
            const size_t m = (size_t)(m0 + ty4 + i);
            *(float4*)(C + m * N + cn) = make_float4(acc[i][0], acc[i][1], acc[i][2], acc[i][3]);
        }
    } else {
        const float4 om = *(const float4*)(omega + cn);
        const float4 bo = *(const float4*)(bout + cn);
        #pragma unroll
        for (int i = 0; i < 4; ++i) {
            const size_t off = (size_t)(m0 + ty4 + i) * 256 + cn;
            float4 f;
            f.x = acc[i][0] + om.x + bo.x;
            f.y = acc[i][1] + om.y + bo.y;
            f.z = acc[i][2] + om.z + bo.z;
            f.w = acc[i][3] + om.w + bo.w;
            if (stage == 0) {
                *(float4*)(kacc + off) = f;
                float4 xv = *(const float4*)(xin + off);
                const float c = 0.5f * DT_;
                *(float4*)(xstage + off) =
                    make_float4(xv.x + c*f.x, xv.y + c*f.y, xv.z + c*f.z, xv.w + c*f.w);
            } else if (stage < 3) {
                float4 ka = *(const float4*)(kacc + off);
                ka.x += 2.0f*f.x; ka.y += 2.0f*f.y; ka.z += 2.0f*f.z; ka.w += 2.0f*f.w;
                *(float4*)(kacc + off) = ka;
                float4 xv = *(const float4*)(xin + off);
                const float c = (stage == 1) ? 0.5f * DT_ : DT_;
                *(float4*)(xstage + off) =
                    make_float4(xv.x + c*f.x, xv.y + c*f.y, xv.z + c*f.z, xv.w + c*f.w);
            } else {
                float4 ka = *(const float4*)(kacc + off);
                float4 xv = *(const float4*)(xin + off);
                const float c = DT_ / 6.0f;
                *(float4*)(xout + off) = make_float4(xv.x + c*(ka.x + f.x),
                                                     xv.y + c*(ka.y + f.y),
                                                     xv.z + c*(ka.z + f.z),
                                                     xv.w + c*(ka.w + f.w));
            }
        }
    }
}

// ---------------- F = sin(Q K^T) K per (b,h); 64-row tile per block ----------------
__global__ __launch_bounds__(256)
void kuramoto_attn(const float* __restrict__ qk, float* __restrict__ force) {
    __shared__ float Qt[64][68];  // [d][i]
    __shared__ float Kt[64][68];  // [d][j]
    __shared__ float Kj[64][68];  // [j][d]
    __shared__ float Pt[64][68];  // [j][i]
    const int i0 = blockIdx.x * 64;
    const int h  = blockIdx.y;
    const int b  = blockIdx.z;
    const float* qbase = qk + (size_t)b * TT * 512 + h * 64;
    const float* kbase = qbase + 256;
    const int t  = threadIdx.x;
    const int lr = t >> 4;
    const int lc = (t & 15) << 2;
    const int ty4 = (t >> 4) << 2;
    const int tx4 = (t & 15) << 2;

    #pragma unroll
    for (int rr = 0; rr < 4; ++rr) {
        const int r = lr + rr * 16;
        float4 v = *(const float4*)(qbase + (size_t)(i0 + r) * 512 + lc);
        Qt[lc+0][r] = v.x; Qt[lc+1][r] = v.y; Qt[lc+2][r] = v.z; Qt[lc+3][r] = v.w;
    }

    float F[4][4] = {};
    for (int j0 = 0; j0 < TT; j0 += 64) {
        __syncthreads();   // prev iter's reads of Kt/Kj/Pt done (and Qt visible on iter 0)
        #pragma unroll
        for (int rr = 0; rr < 4; ++rr) {
            const int r = lr + rr * 16;
            float4 v = *(const float4*)(kbase + (size_t)(j0 + r) * 512 + lc);
            Kt[lc+0][r] = v.x; Kt[lc+1][r] = v.y; Kt[lc+2][r] = v.z; Kt[lc+3][r] = v.w;
            *(float4*)&Kj[r][lc] = v;
        }
        __syncthreads();
        float S[4][4] = {};
        #pragma unroll 8
        for (int d = 0; d < 64; ++d) {
            float4 qv = *(const float4*)&Qt[d][ty4];
            float4 kv = *(const float4*)&Kt[d][tx4];
            const float q[4] = {qv.x, qv.y, qv.z, qv.w};
            const float k[4] = {kv.x, kv.y, kv.z, kv.w};
            #pragma unroll
            for (int i = 0; i < 4; ++i)
                #pragma unroll
                for (int j = 0; j < 4; ++j)
                    S[i][j] = fmaf(q[i], k[j], S[i][j]);
        }
        #pragma unroll
        for (int jj = 0; jj < 4; ++jj) {
            float4 pv;
            pv.x = __sinf(S[0][jj]);
            pv.y = __sinf(S[1][jj]);
            pv.z = __sinf(S[2][jj]);
            pv.w = __sinf(S[3][jj]);
            *(float4*)&Pt[tx4 + jj][ty4] = pv;   // Pt[j][i]
        }
        __syncthreads();
        #pragma unroll 8
        for (int j = 0; j < 64; ++j) {
            float4 pv = *(const float4*)&Pt[j][ty4];
            float4 kv = *(const float4*)&Kj[j][tx4];
            const float p[4] = {pv.x, pv.y, pv.z, pv.w};
            const float k[4] = {kv.x, kv.y, kv.z, kv.w};
            #pragma unroll
            for (int i = 0; i < 4; ++i)
                #pragma unroll
                for (int d = 0; d < 4; ++d)
                    F[i][d] = fmaf(p[i], k[d], F[i][d]);
        }
    }
    float* fb = force + (size_t)b * TT * 256 + h * 64;
    #pragma unroll
    for (int ii = 0; ii < 4; ++ii) {
        *(float4*)(fb + (size_t)(i0 + ty4 + ii) * 256 + tx4) =
            make_float4(F[ii][0], F[ii][1], F[ii][2], F[ii][3]);
    }
}

extern "C" void kernel_launch(void* const* d_in, const int* in_sizes, int n_in,
                              void* d_out, int out_size, void* d_ws, size_t ws_size,
                              hipStream_t stream) {
    const float* z     = (const float*)d_in[0];
    const float* omega = (const float*)d_in[1];
    const float* Wqk   = (const float*)d_in[2];
    const float* Wout  = (const float*)d_in[3];
    const float* bout  = (const float*)d_in[4];

    float* x     = (float*)d_ws;                 // [BT, 256]
    float* xs    = x     + (size_t)BT * 256;     // [BT, 256] stage input
    float* qk    = xs    + (size_t)BT * 256;     // [BT, 512]
    float* force = qk    + (size_t)BT * 512;     // [BT, 256]
    float* kacc  = force + (size_t)BT * 256;     // [BT, 256]

    for (int step = 0; step < 4; ++step) {
        l2norm_rows<<<BT / 4, 256, 0, stream>>>(step == 0 ? z : x, x);
        for (int s = 0; s < 4; ++s) {
            const float* xin_s = (s == 0) ? x : xs;
            // qk = xin_s @ Wqk^T
            gemm_nt_fused<<<dim3(BT / 64, 8), 256, 0, stream>>>(
                xin_s, Wqk, qk, 512,
                nullptr, nullptr, nullptr, nullptr, nullptr, nullptr, -1);
            qk_headnorm<<<BT, 256, 0, stream>>>(qk);
            kuramoto_attn<<<dim3(TT / 64, NH, NB), 256, 0, stream>>>(qk, force);
            // k_s = omega + force @ Wout^T + bout, fused RK4 update
            gemm_nt_fused<<<dim3(BT / 64, 4), 256, 0, stream>>>(
                force, Wout, nullptr, 256,
                omega, bout, x, kacc, xs, x, s);
        }
    }
    l2norm_rows<<<BT / 4, 256, 0, stream>>>(x, (float*)d_out);
}

// Round 3
// 2378.449 us; speedup vs baseline: 2.2990x; 2.2990x over previous
//
#include <hip/hip_runtime.h>
#include <cmath>

#define NB 4
#define TT 2048
#define DD 256
#define NH 4
#define BT (NB*TT)   // 8192 rows

static constexpr float DT_ = 0.25f;

typedef _Float16 f16x8 __attribute__((ext_vector_type(8)));
typedef _Float16 f16x4 __attribute__((ext_vector_type(4)));
typedef float    f32x4 __attribute__((ext_vector_type(4)));

// Per-(b,h) fp16 array element count: 16 bh * 2048 rows * 64 dims.
// R2 BUG: this was sized BT*64 (4x too small) -> Qh/Kh/Ktr aliased -> garbage.
static constexpr size_t HSZ = (size_t)NB * NH * TT * 64;   // 2,097,152 halves = 4 MB

// ---------------- row-wise l2 norm over D=256 (one wave per row) ----------------
__global__ __launch_bounds__(256)
void l2norm_rows(const float* __restrict__ src, float* __restrict__ dst) {
    const int wave = threadIdx.x >> 6;
    const int lane = threadIdx.x & 63;
    const size_t row = (size_t)blockIdx.x * 4 + wave;
    float4 v = ((const float4*)(src + row * DD))[lane];
    float ss = v.x*v.x + v.y*v.y + v.z*v.z + v.w*v.w;
    #pragma unroll
    for (int off = 32; off; off >>= 1) ss += __shfl_xor(ss, off, 64);
    const float inv = 1.0f / fmaxf(sqrtf(ss), 1e-12f);
    v.x *= inv; v.y *= inv; v.z *= inv; v.w *= inv;
    ((float4*)(dst + row * DD))[lane] = v;
}

// ---------------- C = A[M,256] * W[N,256]^T, 64x64 tile, 4x4 per thread ----------------
// stage -1 : qk GEMM (grid.y=8). Epilogue fuses per-head l2norm and emits
//            split-fp16 Qhi/Qlo/Khi/Klo [bh][2048][64]; for k-tiles also
//            KtrH/KtrL [bh][64][2048] (transposed, for attn GEMM2 B-frags).
// stage 0..3: out GEMM (grid.y=4); f = acc + omega + bout; RK4 epilogue.
__global__ __launch_bounds__(256)
void gemm_nt_fused(const float* __restrict__ A, const float* __restrict__ W,
                   const float* __restrict__ omega, const float* __restrict__ bout,
                   const float* __restrict__ xin, float* __restrict__ kacc,
                   float* __restrict__ xstage, float* __restrict__ xout,
                   _Float16* __restrict__ Qhi, _Float16* __restrict__ Qlo,
                   _Float16* __restrict__ Khi, _Float16* __restrict__ Klo,
                   _Float16* __restrict__ KtrH, _Float16* __restrict__ KtrL,
                   int stage)
{
    __shared__ float At[64][68];
    __shared__ float Wt[64][68];
    const int m0 = blockIdx.x * 64, n0 = blockIdx.y * 64;
    const int t  = threadIdx.x;
    const int lr = t >> 4;
    const int lc = (t & 15) << 2;
    const int ty4 = (t >> 4) << 2;   // row offset of 4x4 tile
    const int tx4 = (t & 15) << 2;   // col offset of 4x4 tile
    float acc[4][4] = {};
    for (int k0 = 0; k0 < 256; k0 += 64) {
        __syncthreads();
        #pragma unroll
        for (int rr = 0; rr < 4; ++rr) {
            const int r = lr + rr * 16;
            float4 av = *(const float4*)(A + (size_t)(m0 + r) * 256 + k0 + lc);
            At[lc+0][r] = av.x; At[lc+1][r] = av.y; At[lc+2][r] = av.z; At[lc+3][r] = av.w;
            float4 wv = *(const float4*)(W + (size_t)(n0 + r) * 256 + k0 + lc);
            Wt[lc+0][r] = wv.x; Wt[lc+1][r] = wv.y; Wt[lc+2][r] = wv.z; Wt[lc+3][r] = wv.w;
        }
        __syncthreads();
        #pragma unroll 8
        for (int k = 0; k < 64; ++k) {
            float4 av = *(const float4*)&At[k][ty4];
            float4 wv = *(const float4*)&Wt[k][tx4];
            const float a[4] = {av.x, av.y, av.z, av.w};
            const float w[4] = {wv.x, wv.y, wv.z, wv.w};
            #pragma unroll
            for (int i = 0; i < 4; ++i)
                #pragma unroll
                for (int j = 0; j < 4; ++j)
                    acc[i][j] = fmaf(a[i], w[j], acc[i][j]);
        }
    }
    if (stage < 0) {
        // ---- fused per-head l2norm + split-fp16 emit (n-tile == one head) ----
        __syncthreads();   // compute reads of At/Wt done; reuse as transpose tiles
        float ss[4];
        #pragma unroll
        for (int i = 0; i < 4; ++i)
            ss[i] = acc[i][0]*acc[i][0] + acc[i][1]*acc[i][1]
                  + acc[i][2]*acc[i][2] + acc[i][3]*acc[i][3];
        #pragma unroll
        for (int off = 1; off < 16; off <<= 1) {
            #pragma unroll
            for (int i = 0; i < 4; ++i) ss[i] += __shfl_xor(ss[i], off, 64);
        }
        const int  b    = m0 >> 11;
        const int  h    = (n0 >> 6) & 3;
        const bool is_k = (n0 >= 256);
        const size_t bh   = (size_t)b * NH + h;
        const size_t base = bh * (size_t)TT * 64;
        _Float16* dhi = (is_k ? Khi : Qhi) + base;
        _Float16* dlo = (is_k ? Klo : Qlo) + base;
        _Float16* TtH = (_Float16*)At;   // [64 d][72] transpose staging (hi)
        _Float16* TtL = (_Float16*)Wt;   // [64 d][72] transpose staging (lo)
        #pragma unroll
        for (int i = 0; i < 4; ++i) {
            const float inv = 1.0f / fmaxf(sqrtf(ss[i]), 1e-12f);
            f16x4 hv, lv;
            #pragma unroll
            for (int j = 0; j < 4; ++j) {
                const float v = acc[i][j] * inv;
                hv[j] = (_Float16)v;
                lv[j] = (_Float16)(v - (float)hv[j]);   // exact residual, fp16-rounded
            }
            const int row = (m0 & (TT-1)) + ty4 + i;
            *(f16x4*)(dhi + (size_t)row * 64 + tx4) = hv;
            *(f16x4*)(dlo + (size_t)row * 64 + tx4) = lv;
            if (is_k) {
                #pragma unroll
                for (int j = 0; j < 4; ++j) {
                    TtH[(tx4+j)*72 + ty4+i] = hv[j];
                    TtL[(tx4+j)*72 + ty4+i] = lv[j];
                }
            }
        }
        if (is_k) {
            __syncthreads();
            const int d  = t >> 2;
            const int js = (t & 3) * 16;
            const size_t tb = bh * (size_t)64 * TT + (size_t)d * TT + (m0 & (TT-1)) + js;
            *(uint4*)(KtrH + tb)     = *(uint4*)&TtH[d*72 + js];
            *(uint4*)(KtrH + tb + 8) = *(uint4*)&TtH[d*72 + js + 8];
            *(uint4*)(KtrL + tb)     = *(uint4*)&TtL[d*72 + js];
            *(uint4*)(KtrL + tb + 8) = *(uint4*)&TtL[d*72 + js + 8];
        }
    } else {
        const int cn = n0 + tx4;
        const float4 om = *(const float4*)(omega + cn);
        const float4 bo = *(const float4*)(bout + cn);
        #pragma unroll
        for (int i = 0; i < 4; ++i) {
            const size_t off = (size_t)(m0 + ty4 + i) * 256 + cn;
            float4 f;
            f.x = acc[i][0] + om.x + bo.x;
            f.y = acc[i][1] + om.y + bo.y;
            f.z = acc[i][2] + om.z + bo.z;
            f.w = acc[i][3] + om.w + bo.w;
            if (stage == 0) {
                *(float4*)(kacc + off) = f;
                float4 xv = *(const float4*)(xin + off);
                const float c = 0.5f * DT_;
                *(float4*)(xstage + off) =
                    make_float4(xv.x + c*f.x, xv.y + c*f.y, xv.z + c*f.z, xv.w + c*f.w);
            } else if (stage < 3) {
                float4 ka = *(const float4*)(kacc + off);
                ka.x += 2.0f*f.x; ka.y += 2.0f*f.y; ka.z += 2.0f*f.z; ka.w += 2.0f*f.w;
                *(float4*)(kacc + off) = ka;
                float4 xv = *(const float4*)(xin + off);
                const float c = (stage == 1) ? 0.5f * DT_ : DT_;
                *(float4*)(xstage + off) =
                    make_float4(xv.x + c*f.x, xv.y + c*f.y, xv.z + c*f.z, xv.w + c*f.w);
            } else {
                float4 ka = *(const float4*)(kacc + off);
                float4 xv = *(const float4*)(xin + off);
                const float c = DT_ / 6.0f;
                *(float4*)(xout + off) = make_float4(xv.x + c*(ka.x + f.x),
                                                     xv.y + c*(ka.y + f.y),
                                                     xv.z + c*(ka.z + f.z),
                                                     xv.w + c*(ka.w + f.w));
            }
        }
    }
}

// ---------------- F = sin(Q K^T) K via split-fp16 MFMA (3-term hi/lo) ----------------
// 4 waves, each owns 16 i-rows. Fragment layouts (guide §3, HW-verified):
//   A-frag:  A[m=lane&15][k=quad*8+idx]
//   B-frag:  B[k=quad*8+idx][n=lane&15]
//   C/D:     D[row=quad*4+reg][col=lane&15]
__global__ __launch_bounds__(256)
void kuramoto_attn(const _Float16* __restrict__ Qhi, const _Float16* __restrict__ Qlo,
                   const _Float16* __restrict__ Khi, const _Float16* __restrict__ Klo,
                   const _Float16* __restrict__ KtrH, const _Float16* __restrict__ KtrL,
                   float* __restrict__ force)
{
    __shared__ _Float16 KjH[64 * 72];     // [j][d] hi
    __shared__ _Float16 KjL[64 * 72];     // [j][d] lo
    __shared__ _Float16 KdH[64 * 72];     // [d][j] hi
    __shared__ _Float16 KdL[64 * 72];     // [d][j] lo
    __shared__ _Float16 PwH[4][16 * 72];  // per-wave sin(S) hi [i_loc][j]
    __shared__ _Float16 PwL[4][16 * 72];  // per-wave sin(S) lo
    const int h = blockIdx.y, b = blockIdx.z;
    const size_t bh    = (size_t)b * NH + h;
    const size_t base  = bh * (size_t)TT * 64;
    const size_t tbase = bh * (size_t)64 * TT;
    const int t = threadIdx.x;
    const int w = t >> 6;
    const int l = t & 63;
    const int lr = l & 15;       // m/n index within fragment
    const int lq = l >> 4;       // quad
    const int i0 = blockIdx.x * 64 + w * 16;

    // Q fragments (hi+lo), 16 rows x 64 k, live whole kernel
    const size_t qoff = base + (size_t)(i0 + lr) * 64 + lq * 8;
    f16x8 qh0 = *(const f16x8*)(Qhi + qoff);
    f16x8 qh1 = *(const f16x8*)(Qhi + qoff + 32);
    f16x8 ql0 = *(const f16x8*)(Qlo + qoff);
    f16x8 ql1 = *(const f16x8*)(Qlo + qoff + 32);

    f32x4 Facc[4];
    #pragma unroll
    for (int nt = 0; nt < 4; ++nt) Facc[nt] = (f32x4){0.f, 0.f, 0.f, 0.f};

    const int sr = t >> 3;       // staging row 0..31 (+32)
    const int so = (t & 7) * 8;  // staging octet offset (halves)

    for (int j0 = 0; j0 < TT; j0 += 64) {
        __syncthreads();   // previous iteration's LDS reads complete
        {   // stage K tile: [j][d] (hi/lo) and [d][j] (hi/lo), all coalesced
            *(uint4*)&KjH[sr * 72 + so]        = *(const uint4*)(Khi + base + (size_t)(j0 + sr) * 64 + so);
            *(uint4*)&KjH[(sr + 32) * 72 + so] = *(const uint4*)(Khi + base + (size_t)(j0 + sr + 32) * 64 + so);
            *(uint4*)&KjL[sr * 72 + so]        = *(const uint4*)(Klo + base + (size_t)(j0 + sr) * 64 + so);
            *(uint4*)&KjL[(sr + 32) * 72 + so] = *(const uint4*)(Klo + base + (size_t)(j0 + sr + 32) * 64 + so);
            *(uint4*)&KdH[sr * 72 + so]        = *(const uint4*)(KtrH + tbase + (size_t)sr * TT + j0 + so);
            *(uint4*)&KdH[(sr + 32) * 72 + so] = *(const uint4*)(KtrH + tbase + (size_t)(sr + 32) * TT + j0 + so);
            *(uint4*)&KdL[sr * 72 + so]        = *(const uint4*)(KtrL + tbase + (size_t)sr * TT + j0 + so);
            *(uint4*)&KdL[(sr + 32) * 72 + so] = *(const uint4*)(KtrL + tbase + (size_t)(sr + 32) * TT + j0 + so);
        }
        __syncthreads();
        // GEMM1: S = qh*kh + qh*kl + ql*kh  (fp32 accum)
        f32x4 S[4];
        #pragma unroll
        for (int nt = 0; nt < 4; ++nt) {
            S[nt] = (f32x4){0.f, 0.f, 0.f, 0.f};
            f16x8 bh0 = *(const f16x8*)&KjH[(16*nt + lr) * 72 + lq * 8];
            f16x8 bh1 = *(const f16x8*)&KjH[(16*nt + lr) * 72 + 32 + lq * 8];
            f16x8 bl0 = *(const f16x8*)&KjL[(16*nt + lr) * 72 + lq * 8];
            f16x8 bl1 = *(const f16x8*)&KjL[(16*nt + lr) * 72 + 32 + lq * 8];
            S[nt] = __builtin_amdgcn_mfma_f32_16x16x32_f16(qh0, bh0, S[nt], 0, 0, 0);
            S[nt] = __builtin_amdgcn_mfma_f32_16x16x32_f16(qh1, bh1, S[nt], 0, 0, 0);
            S[nt] = __builtin_amdgcn_mfma_f32_16x16x32_f16(qh0, bl0, S[nt], 0, 0, 0);
            S[nt] = __builtin_amdgcn_mfma_f32_16x16x32_f16(qh1, bl1, S[nt], 0, 0, 0);
            S[nt] = __builtin_amdgcn_mfma_f32_16x16x32_f16(ql0, bh0, S[nt], 0, 0, 0);
            S[nt] = __builtin_amdgcn_mfma_f32_16x16x32_f16(ql1, bh1, S[nt], 0, 0, 0);
        }
        // sin in fp32, split to hi/lo, C-layout -> A-layout via per-wave LDS
        #pragma unroll
        for (int nt = 0; nt < 4; ++nt) {
            #pragma unroll
            for (int r = 0; r < 4; ++r) {
                const float p = __sinf(S[nt][r]);
                const _Float16 ph = (_Float16)p;
                PwH[w][(4*lq + r) * 72 + 16*nt + lr] = ph;
                PwL[w][(4*lq + r) * 72 + 16*nt + lr] = (_Float16)(p - (float)ph);
            }
        }
        f16x8 ph0 = *(const f16x8*)&PwH[w][lr * 72 + lq * 8];
        f16x8 ph1 = *(const f16x8*)&PwH[w][lr * 72 + 32 + lq * 8];
        f16x8 pl0 = *(const f16x8*)&PwL[w][lr * 72 + lq * 8];
        f16x8 pl1 = *(const f16x8*)&PwL[w][lr * 72 + 32 + lq * 8];
        // GEMM2: F += ph*kh + ph*kl + pl*kh
        #pragma unroll
        for (int nt = 0; nt < 4; ++nt) {
            f16x8 kh0 = *(const f16x8*)&KdH[(16*nt + lr) * 72 + lq * 8];
            f16x8 kh1 = *(const f16x8*)&KdH[(16*nt + lr) * 72 + 32 + lq * 8];
            f16x8 kl0 = *(const f16x8*)&KdL[(16*nt + lr) * 72 + lq * 8];
            f16x8 kl1 = *(const f16x8*)&KdL[(16*nt + lr) * 72 + 32 + lq * 8];
            Facc[nt] = __builtin_amdgcn_mfma_f32_16x16x32_f16(ph0, kh0, Facc[nt], 0, 0, 0);
            Facc[nt] = __builtin_amdgcn_mfma_f32_16x16x32_f16(ph1, kh1, Facc[nt], 0, 0, 0);
            Facc[nt] = __builtin_amdgcn_mfma_f32_16x16x32_f16(ph0, kl0, Facc[nt], 0, 0, 0);
            Facc[nt] = __builtin_amdgcn_mfma_f32_16x16x32_f16(ph1, kl1, Facc[nt], 0, 0, 0);
            Facc[nt] = __builtin_amdgcn_mfma_f32_16x16x32_f16(pl0, kh0, Facc[nt], 0, 0, 0);
            Facc[nt] = __builtin_amdgcn_mfma_f32_16x16x32_f16(pl1, kh1, Facc[nt], 0, 0, 0);
        }
    }
    // write F (fp32): row = i0 + 4*lq + r, col = h*64 + 16*nt + lr
    float* fb = force + ((size_t)b * TT + i0 + 4*lq) * 256 + h * 64 + lr;
    #pragma unroll
    for (int nt = 0; nt < 4; ++nt)
        #pragma unroll
        for (int r = 0; r < 4; ++r)
            fb[(size_t)r * 256 + nt * 16] = Facc[nt][r];
}

extern "C" void kernel_launch(void* const* d_in, const int* in_sizes, int n_in,
                              void* d_out, int out_size, void* d_ws, size_t ws_size,
                              hipStream_t stream) {
    const float* z     = (const float*)d_in[0];
    const float* omega = (const float*)d_in[1];
    const float* Wqk   = (const float*)d_in[2];
    const float* Wout  = (const float*)d_in[3];
    const float* bout  = (const float*)d_in[4];

    float* x     = (float*)d_ws;                 // [BT, 256]
    float* xs    = x     + (size_t)BT * 256;     // [BT, 256] stage input
    float* force = xs    + (size_t)BT * 256;     // [BT, 256]
    float* kacc  = force + (size_t)BT * 256;     // [BT, 256]
    _Float16* Qhi  = (_Float16*)(kacc + (size_t)BT * 256);
    _Float16* Qlo  = Qhi  + HSZ;
    _Float16* Khi  = Qlo  + HSZ;
    _Float16* Klo  = Khi  + HSZ;
    _Float16* KtrH = Klo  + HSZ;
    _Float16* KtrL = KtrH + HSZ;    // total ws: 32 MB fp32 + 24 MB fp16 = 56 MB

    for (int step = 0; step < 4; ++step) {
        l2norm_rows<<<BT / 4, 256, 0, stream>>>(step == 0 ? z : x, x);
        for (int s = 0; s < 4; ++s) {
            const float* xin_s = (s == 0) ? x : xs;
            gemm_nt_fused<<<dim3(BT / 64, 8), 256, 0, stream>>>(
                xin_s, Wqk, nullptr, nullptr, nullptr, nullptr, nullptr, nullptr,
                Qhi, Qlo, Khi, Klo, KtrH, KtrL, -1);
            kuramoto_attn<<<dim3(TT / 64, NH, NB), 256, 0, stream>>>(
                Qhi, Qlo, Khi, Klo, KtrH, KtrL, force);
            gemm_nt_fused<<<dim3(BT / 64, 4), 256, 0, stream>>>(
                force, Wout, omega, bout, x, kacc, xs, x,
                nullptr, nullptr, nullptr, nullptr, nullptr, nullptr, s);
        }
    }
    l2norm_rows<<<BT / 4, 256, 0, stream>>>(x, (float*)d_out);
}

// Round 4
// 1901.302 us; speedup vs baseline: 2.8759x; 1.2510x over previous
//
#include <hip/hip_runtime.h>
#include <cmath>

#define NB 4
#define TT 2048
#define DD 256
#define NH 4
#define BT (NB*TT)   // 8192 rows

static constexpr float DT_ = 0.25f;

typedef _Float16 f16x8 __attribute__((ext_vector_type(8)));
typedef _Float16 f16x4 __attribute__((ext_vector_type(4)));
typedef float    f32x4 __attribute__((ext_vector_type(4)));

static constexpr size_t HSZ = (size_t)NB * NH * TT * 64;   // per split Q/K array: 2M halves

// ---------------- split W into fp16 hi/lo (runs once per launch) ----------------
__global__ __launch_bounds__(256)
void split_weights(const float* __restrict__ Wqk, const float* __restrict__ Wout,
                   _Float16* __restrict__ WqkH, _Float16* __restrict__ WqkL,
                   _Float16* __restrict__ WoutH, _Float16* __restrict__ WoutL)
{
    const int idx = blockIdx.x * 256 + threadIdx.x;   // float4 group index
    const float4 v = (idx < 32768) ? ((const float4*)Wqk)[idx]
                                   : ((const float4*)Wout)[idx - 32768];
    f16x4 h, l;
    h[0]=(_Float16)v.x; l[0]=(_Float16)(v.x-(float)h[0]);
    h[1]=(_Float16)v.y; l[1]=(_Float16)(v.y-(float)h[1]);
    h[2]=(_Float16)v.z; l[2]=(_Float16)(v.z-(float)h[2]);
    h[3]=(_Float16)v.w; l[3]=(_Float16)(v.w-(float)h[3]);
    if (idx < 32768) { ((f16x4*)WqkH)[idx] = h; ((f16x4*)WqkL)[idx] = l; }
    else { ((f16x4*)WoutH)[idx-32768] = h; ((f16x4*)WoutL)[idx-32768] = l; }
}

// ---------------- row-wise l2 norm over D=256; optional fp16 split emit ----------------
__global__ __launch_bounds__(256)
void l2norm_rows(const float* __restrict__ src, float* __restrict__ dst,
                 _Float16* __restrict__ dstH, _Float16* __restrict__ dstL) {
    const int wave = threadIdx.x >> 6;
    const int lane = threadIdx.x & 63;
    const size_t row = (size_t)blockIdx.x * 4 + wave;
    float4 v = ((const float4*)(src + row * DD))[lane];
    float ss = v.x*v.x + v.y*v.y + v.z*v.z + v.w*v.w;
    #pragma unroll
    for (int off = 32; off; off >>= 1) ss += __shfl_xor(ss, off, 64);
    const float inv = 1.0f / fmaxf(sqrtf(ss), 1e-12f);
    v.x *= inv; v.y *= inv; v.z *= inv; v.w *= inv;
    ((float4*)(dst + row * DD))[lane] = v;
    if (dstH != nullptr) {
        f16x4 h, l;
        h[0]=(_Float16)v.x; l[0]=(_Float16)(v.x-(float)h[0]);
        h[1]=(_Float16)v.y; l[1]=(_Float16)(v.y-(float)h[1]);
        h[2]=(_Float16)v.z; l[2]=(_Float16)(v.z-(float)h[2]);
        h[3]=(_Float16)v.w; l[3]=(_Float16)(v.w-(float)h[3]);
        ((f16x4*)(dstH + row * DD))[lane] = h;
        ((f16x4*)(dstL + row * DD))[lane] = l;
    }
}

// ---------------- split-fp16 MFMA GEMM: C = A[M,256] * W[N,256]^T ----------------
// Block 256 thr / 4 waves; tile 128m x 64n; K-loop 4 chunks of 64 via LDS.
// stage -1 : qk GEMM (grid (64,8)); epilogue = per-head l2norm + Q/K/Ktr split emit.
// stage 0-3: out GEMM (grid (64,4)); epilogue = f=acc+omega+bout, RK4 update.
// Fragment layouts (HW-verified): A[m=lane&15][k=quad*8+idx], B[k=quad*8+idx][n=lane&15],
// D[row=quad*4+reg][col=lane&15].
__global__ __launch_bounds__(256)
void gemm_mfma(const _Float16* __restrict__ AH, const _Float16* __restrict__ AL,
               const _Float16* __restrict__ BH, const _Float16* __restrict__ BL,
               const float* __restrict__ omega, const float* __restrict__ bout,
               const float* __restrict__ xin, float* __restrict__ kacc,
               _Float16* __restrict__ xsH, _Float16* __restrict__ xsL,
               float* __restrict__ xout,
               _Float16* __restrict__ Qhi, _Float16* __restrict__ Qlo,
               _Float16* __restrict__ Khi, _Float16* __restrict__ Klo,
               _Float16* __restrict__ KtrH, _Float16* __restrict__ KtrL,
               int stage)
{
    __shared__ _Float16 Ah[128 * 72];   // [m][k-chunk], pitch 72 halves (144 B, 16B-aligned)
    __shared__ _Float16 Al[128 * 72];
    __shared__ _Float16 Bh[64 * 72];
    __shared__ _Float16 Bl[64 * 72];
    const int m0 = blockIdx.x * 128, n0 = blockIdx.y * 64;
    const int t  = threadIdx.x;
    const int w  = t >> 6;
    const int l  = t & 63;
    const int lr = l & 15;
    const int lq = l >> 4;

    f32x4 acc[2][4];
    #pragma unroll
    for (int s = 0; s < 2; ++s)
        #pragma unroll
        for (int nt = 0; nt < 4; ++nt) acc[s][nt] = (f32x4){0.f,0.f,0.f,0.f};

    for (int kc = 0; kc < 4; ++kc) {
        const int k0 = kc * 64;
        __syncthreads();   // previous chunk's LDS reads complete
        #pragma unroll
        for (int s2 = 0; s2 < 4; ++s2) {        // A: 1024 16B segs (128 rows x 8)
            const int idx = t + 256 * s2;
            const int r = idx >> 3, c8 = (idx & 7) * 8;
            *(uint4*)&Ah[r * 72 + c8] = *(const uint4*)(AH + (size_t)(m0 + r) * 256 + k0 + c8);
            *(uint4*)&Al[r * 72 + c8] = *(const uint4*)(AL + (size_t)(m0 + r) * 256 + k0 + c8);
        }
        #pragma unroll
        for (int s2 = 0; s2 < 2; ++s2) {        // B: 512 16B segs (64 rows x 8)
            const int idx = t + 256 * s2;
            const int r = idx >> 3, c8 = (idx & 7) * 8;
            *(uint4*)&Bh[r * 72 + c8] = *(const uint4*)(BH + (size_t)(n0 + r) * 256 + k0 + c8);
            *(uint4*)&Bl[r * 72 + c8] = *(const uint4*)(BL + (size_t)(n0 + r) * 256 + k0 + c8);
        }
        __syncthreads();
        #pragma unroll
        for (int c = 0; c < 2; ++c) {           // k-sub 32
            f16x8 ah[2], al[2], bh[4], bl[4];
            #pragma unroll
            for (int s = 0; s < 2; ++s) {
                ah[s] = *(const f16x8*)&Ah[(32*w + 16*s + lr) * 72 + 32*c + 8*lq];
                al[s] = *(const f16x8*)&Al[(32*w + 16*s + lr) * 72 + 32*c + 8*lq];
            }
            #pragma unroll
            for (int nt = 0; nt < 4; ++nt) {
                bh[nt] = *(const f16x8*)&Bh[(16*nt + lr) * 72 + 32*c + 8*lq];
                bl[nt] = *(const f16x8*)&Bl[(16*nt + lr) * 72 + 32*c + 8*lq];
            }
            #pragma unroll
            for (int s = 0; s < 2; ++s)
                #pragma unroll
                for (int nt = 0; nt < 4; ++nt) {
                    acc[s][nt] = __builtin_amdgcn_mfma_f32_16x16x32_f16(ah[s], bh[nt], acc[s][nt], 0, 0, 0);
                    acc[s][nt] = __builtin_amdgcn_mfma_f32_16x16x32_f16(ah[s], bl[nt], acc[s][nt], 0, 0, 0);
                    acc[s][nt] = __builtin_amdgcn_mfma_f32_16x16x32_f16(al[s], bh[nt], acc[s][nt], 0, 0, 0);
                }
        }
    }

    if (stage < 0) {
        // ---- per-head l2norm + split-fp16 Q/K/Ktr emit (n-tile == one head) ----
        float ss[2][4];
        #pragma unroll
        for (int s = 0; s < 2; ++s)
            #pragma unroll
            for (int r = 0; r < 4; ++r) {
                float v = 0.f;
                #pragma unroll
                for (int nt = 0; nt < 4; ++nt) v += acc[s][nt][r] * acc[s][nt][r];
                ss[s][r] = v;
            }
        #pragma unroll
        for (int off = 1; off < 16; off <<= 1)
            #pragma unroll
            for (int s = 0; s < 2; ++s)
                #pragma unroll
                for (int r = 0; r < 4; ++r)
                    ss[s][r] += __shfl_xor(ss[s][r], off, 64);
        const int  b    = m0 >> 11;
        const int  h    = (n0 >> 6) & 3;
        const bool is_k = (n0 >= 256);
        const size_t bhi = (size_t)b * NH + h;
        _Float16* dhi = (is_k ? Khi : Qhi) + bhi * (size_t)TT * 64;
        _Float16* dlo = (is_k ? Klo : Qlo) + bhi * (size_t)TT * 64;
        const int mloc = m0 & (TT - 1);
        #pragma unroll
        for (int s = 0; s < 2; ++s) {
            const int r0 = 32*w + 16*s + 4*lq;
            float inv[4];
            #pragma unroll
            for (int r = 0; r < 4; ++r) inv[r] = 1.0f / fmaxf(sqrtf(ss[s][r]), 1e-12f);
            #pragma unroll
            for (int nt = 0; nt < 4; ++nt) {
                const int d = 16*nt + lr;
                f16x4 hv, lv;
                #pragma unroll
                for (int r = 0; r < 4; ++r) {
                    const float val = acc[s][nt][r] * inv[r];
                    hv[r] = (_Float16)val;
                    lv[r] = (_Float16)(val - (float)hv[r]);
                    dhi[(size_t)(mloc + r0 + r) * 64 + d] = hv[r];
                    dlo[(size_t)(mloc + r0 + r) * 64 + d] = lv[r];
                }
                if (is_k) {
                    const size_t tb = bhi * (size_t)64 * TT + (size_t)d * TT + mloc + r0;
                    *(f16x4*)(KtrH + tb) = hv;
                    *(f16x4*)(KtrL + tb) = lv;
                }
            }
        }
    } else {
        // ---- RK4 epilogue: f = acc + omega + bout ----
        #pragma unroll
        for (int s = 0; s < 2; ++s) {
            const int row0 = m0 + 32*w + 16*s + 4*lq;
            #pragma unroll
            for (int nt = 0; nt < 4; ++nt) {
                const int col = n0 + 16*nt + lr;
                const float ob = omega[col] + bout[col];
                #pragma unroll
                for (int r = 0; r < 4; ++r) {
                    const size_t off = (size_t)(row0 + r) * 256 + col;
                    const float f = acc[s][nt][r] + ob;
                    if (stage == 0) {
                        kacc[off] = f;
                        const float xv = xin[off] + 0.125f * f;
                        const _Float16 xh = (_Float16)xv;
                        xsH[off] = xh;
                        xsL[off] = (_Float16)(xv - (float)xh);
                    } else if (stage < 3) {
                        kacc[off] += 2.0f * f;
                        const float c = (stage == 1) ? 0.125f : 0.25f;
                        const float xv = xin[off] + c * f;
                        const _Float16 xh = (_Float16)xv;
                        xsH[off] = xh;
                        xsL[off] = (_Float16)(xv - (float)xh);
                    } else {
                        xout[off] = xin[off] + (DT_ / 6.0f) * (kacc[off] + f);
                    }
                }
            }
        }
    }
}

// ---------------- F = sin(Q K^T) K via split-fp16 MFMA (3-term hi/lo) ----------------
__global__ __launch_bounds__(256)
void kuramoto_attn(const _Float16* __restrict__ Qhi, const _Float16* __restrict__ Qlo,
                   const _Float16* __restrict__ Khi, const _Float16* __restrict__ Klo,
                   const _Float16* __restrict__ KtrH, const _Float16* __restrict__ KtrL,
                   _Float16* __restrict__ FH, _Float16* __restrict__ FL)
{
    __shared__ _Float16 KjH[64 * 72];     // [j][d] hi
    __shared__ _Float16 KjL[64 * 72];     // [j][d] lo
    __shared__ _Float16 KdH[64 * 72];     // [d][j] hi
    __shared__ _Float16 KdL[64 * 72];     // [d][j] lo
    __shared__ _Float16 PwH[4][16 * 72];  // per-wave sin(S) hi [i_loc][j]
    __shared__ _Float16 PwL[4][16 * 72];
    const int h = blockIdx.y, b = blockIdx.z;
    const size_t bh    = (size_t)b * NH + h;
    const size_t base  = bh * (size_t)TT * 64;
    const size_t tbase = bh * (size_t)64 * TT;
    const int t = threadIdx.x;
    const int w = t >> 6;
    const int l = t & 63;
    const int lr = l & 15;
    const int lq = l >> 4;
    const int i0 = blockIdx.x * 64 + w * 16;

    const size_t qoff = base + (size_t)(i0 + lr) * 64 + lq * 8;
    f16x8 qh0 = *(const f16x8*)(Qhi + qoff);
    f16x8 qh1 = *(const f16x8*)(Qhi + qoff + 32);
    f16x8 ql0 = *(const f16x8*)(Qlo + qoff);
    f16x8 ql1 = *(const f16x8*)(Qlo + qoff + 32);

    f32x4 Facc[4];
    #pragma unroll
    for (int nt = 0; nt < 4; ++nt) Facc[nt] = (f32x4){0.f, 0.f, 0.f, 0.f};

    const int sr = t >> 3;
    const int so = (t & 7) * 8;

    for (int j0 = 0; j0 < TT; j0 += 64) {
        __syncthreads();
        {
            *(uint4*)&KjH[sr * 72 + so]        = *(const uint4*)(Khi + base + (size_t)(j0 + sr) * 64 + so);
            *(uint4*)&KjH[(sr + 32) * 72 + so] = *(const uint4*)(Khi + base + (size_t)(j0 + sr + 32) * 64 + so);
            *(uint4*)&KjL[sr * 72 + so]        = *(const uint4*)(Klo + base + (size_t)(j0 + sr) * 64 + so);
            *(uint4*)&KjL[(sr + 32) * 72 + so] = *(const uint4*)(Klo + base + (size_t)(j0 + sr + 32) * 64 + so);
            *(uint4*)&KdH[sr * 72 + so]        = *(const uint4*)(KtrH + tbase + (size_t)sr * TT + j0 + so);
            *(uint4*)&KdH[(sr + 32) * 72 + so] = *(const uint4*)(KtrH + tbase + (size_t)(sr + 32) * TT + j0 + so);
            *(uint4*)&KdL[sr * 72 + so]        = *(const uint4*)(KtrL + tbase + (size_t)sr * TT + j0 + so);
            *(uint4*)&KdL[(sr + 32) * 72 + so] = *(const uint4*)(KtrL + tbase + (size_t)(sr + 32) * TT + j0 + so);
        }
        __syncthreads();
        f32x4 S[4];
        #pragma unroll
        for (int nt = 0; nt < 4; ++nt) {
            S[nt] = (f32x4){0.f, 0.f, 0.f, 0.f};
            f16x8 bh0 = *(const f16x8*)&KjH[(16*nt + lr) * 72 + lq * 8];
            f16x8 bh1 = *(const f16x8*)&KjH[(16*nt + lr) * 72 + 32 + lq * 8];
            f16x8 bl0 = *(const f16x8*)&KjL[(16*nt + lr) * 72 + lq * 8];
            f16x8 bl1 = *(const f16x8*)&KjL[(16*nt + lr) * 72 + 32 + lq * 8];
            S[nt] = __builtin_amdgcn_mfma_f32_16x16x32_f16(qh0, bh0, S[nt], 0, 0, 0);
            S[nt] = __builtin_amdgcn_mfma_f32_16x16x32_f16(qh1, bh1, S[nt], 0, 0, 0);
            S[nt] = __builtin_amdgcn_mfma_f32_16x16x32_f16(qh0, bl0, S[nt], 0, 0, 0);
            S[nt] = __builtin_amdgcn_mfma_f32_16x16x32_f16(qh1, bl1, S[nt], 0, 0, 0);
            S[nt] = __builtin_amdgcn_mfma_f32_16x16x32_f16(ql0, bh0, S[nt], 0, 0, 0);
            S[nt] = __builtin_amdgcn_mfma_f32_16x16x32_f16(ql1, bh1, S[nt], 0, 0, 0);
        }
        #pragma unroll
        for (int nt = 0; nt < 4; ++nt) {
            #pragma unroll
            for (int r = 0; r < 4; ++r) {
                const float p = __sinf(S[nt][r]);
                const _Float16 ph = (_Float16)p;
                PwH[w][(4*lq + r) * 72 + 16*nt + lr] = ph;
                PwL[w][(4*lq + r) * 72 + 16*nt + lr] = (_Float16)(p - (float)ph);
            }
        }
        f16x8 ph0 = *(const f16x8*)&PwH[w][lr * 72 + lq * 8];
        f16x8 ph1 = *(const f16x8*)&PwH[w][lr * 72 + 32 + lq * 8];
        f16x8 pl0 = *(const f16x8*)&PwL[w][lr * 72 + lq * 8];
        f16x8 pl1 = *(const f16x8*)&PwL[w][lr * 72 + 32 + lq * 8];
        #pragma unroll
        for (int nt = 0; nt < 4; ++nt) {
            f16x8 kh0 = *(const f16x8*)&KdH[(16*nt + lr) * 72 + lq * 8];
            f16x8 kh1 = *(const f16x8*)&KdH[(16*nt + lr) * 72 + 32 + lq * 8];
            f16x8 kl0 = *(const f16x8*)&KdL[(16*nt + lr) * 72 + lq * 8];
            f16x8 kl1 = *(const f16x8*)&KdL[(16*nt + lr) * 72 + 32 + lq * 8];
            Facc[nt] = __builtin_amdgcn_mfma_f32_16x16x32_f16(ph0, kh0, Facc[nt], 0, 0, 0);
            Facc[nt] = __builtin_amdgcn_mfma_f32_16x16x32_f16(ph1, kh1, Facc[nt], 0, 0, 0);
            Facc[nt] = __builtin_amdgcn_mfma_f32_16x16x32_f16(ph0, kl0, Facc[nt], 0, 0, 0);
            Facc[nt] = __builtin_amdgcn_mfma_f32_16x16x32_f16(ph1, kl1, Facc[nt], 0, 0, 0);
            Facc[nt] = __builtin_amdgcn_mfma_f32_16x16x32_f16(pl0, kh0, Facc[nt], 0, 0, 0);
            Facc[nt] = __builtin_amdgcn_mfma_f32_16x16x32_f16(pl1, kh1, Facc[nt], 0, 0, 0);
        }
    }
    // write F as fp16 splits: row = i0 + 4*lq + r, col = h*64 + 16*nt + lr
    const size_t fo = ((size_t)b * TT + i0 + 4*lq) * 256 + h * 64 + lr;
    #pragma unroll
    for (int nt = 0; nt < 4; ++nt)
        #pragma unroll
        for (int r = 0; r < 4; ++r) {
            const float v = Facc[nt][r];
            const _Float16 vh = (_Float16)v;
            FH[fo + (size_t)r * 256 + nt * 16] = vh;
            FL[fo + (size_t)r * 256 + nt * 16] = (_Float16)(v - (float)vh);
        }
}

extern "C" void kernel_launch(void* const* d_in, const int* in_sizes, int n_in,
                              void* d_out, int out_size, void* d_ws, size_t ws_size,
                              hipStream_t stream) {
    const float* z     = (const float*)d_in[0];
    const float* omega = (const float*)d_in[1];
    const float* Wqk   = (const float*)d_in[2];
    const float* Wout  = (const float*)d_in[3];
    const float* bout  = (const float*)d_in[4];

    float* x    = (float*)d_ws;                  // [BT,256] fp32 state
    float* kacc = x + (size_t)BT * 256;          // [BT,256] fp32 RK4 accumulator
    _Float16* xsH  = (_Float16*)(kacc + (size_t)BT * 256);  // stage-input splits [BT,256]
    _Float16* xsL  = xsH  + (size_t)BT * 256;
    _Float16* FH   = xsL  + (size_t)BT * 256;    // force splits [BT,256]
    _Float16* FL   = FH   + (size_t)BT * 256;
    _Float16* Qhi  = FL   + (size_t)BT * 256;
    _Float16* Qlo  = Qhi  + HSZ;
    _Float16* Khi  = Qlo  + HSZ;
    _Float16* Klo  = Khi  + HSZ;
    _Float16* KtrH = Klo  + HSZ;
    _Float16* KtrL = KtrH + HSZ;
    _Float16* WqkH = KtrL + HSZ;                 // [512,256]
    _Float16* WqkL = WqkH + (size_t)512 * 256;
    _Float16* WoutH= WqkL + (size_t)512 * 256;   // [256,256]
    _Float16* WoutL= WoutH + (size_t)256 * 256;

    split_weights<<<192, 256, 0, stream>>>(Wqk, Wout, WqkH, WqkL, WoutH, WoutL);

    for (int step = 0; step < 4; ++step) {
        l2norm_rows<<<BT / 4, 256, 0, stream>>>(step == 0 ? z : x, x, xsH, xsL);
        for (int s = 0; s < 4; ++s) {
            gemm_mfma<<<dim3(BT / 128, 8), 256, 0, stream>>>(
                xsH, xsL, WqkH, WqkL,
                nullptr, nullptr, nullptr, nullptr, nullptr, nullptr, nullptr,
                Qhi, Qlo, Khi, Klo, KtrH, KtrL, -1);
            kuramoto_attn<<<dim3(TT / 64, NH, NB), 256, 0, stream>>>(
                Qhi, Qlo, Khi, Klo, KtrH, KtrL, FH, FL);
            gemm_mfma<<<dim3(BT / 128, 4), 256, 0, stream>>>(
                FH, FL, WoutH, WoutL,
                omega, bout, x, kacc, xsH, xsL, x,
                nullptr, nullptr, nullptr, nullptr, nullptr, nullptr, s);
        }
    }
    l2norm_rows<<<BT / 4, 256, 0, stream>>>(x, (float*)d_out, nullptr, nullptr);
}